// Round 1
// baseline (438.988 us; speedup 1.0000x reference)
//
#include <hip/hip_runtime.h>

// DWT1DForward db4 periodic J=3, fused single kernel, v3.
// x: (16,64,65536) fp32 -> out concat [lo3(1024*8192), hi1(1024*32768),
//                                      hi2(1024*16384), hi3(1024*8192)]
// Identity: out[i] = sum_t h[t] * x[(2i+t-3) mod N]  per level.
//
// v3: QUAD-granularity processing (4 lo + 4 hi outputs per thread per level
// from a 14-float window, 56 B LDS read per 8 outputs vs v2's 40 B per 4).
// L1 becomes a single strided iteration (518 quads / 512 threads); all
// lo-writes and the L3 stores become aligned float4.

#define N0      65536
#define S       4096
#define BD      512

// out element offsets
#define OFF_LO3 0ul
#define OFF_HI1 8388608ul    // 1024*8192
#define OFF_HI2 41943040ul   // + 1024*32768
#define OFF_HI3 58720256ul   // + 1024*16384

// LDS layout
#define SX_OFF  25           // odd & ==1 mod 4: windows even + b128-aligned
#define SX_SZ   4160         // 25 + 4096 + 31 staged, [4152,4160) zero pad
#define SLO1_SZ 2072         // lo1 phys kk in [0,2072), k = base1-9+kk
#define SLO2_SZ 1032         // lo2 phys jj in [0,1032), j = base2-3+jj

// 8-tap octet: from 14-float window vv[0..13] compute lo/hi at offsets 0..3.
// Output j uses vv[2j .. 2j+7]. 64 FMA, 8 independent accumulator chains.
#define OCT(vv, l, g)                                                 \
    {                                                                 \
        _Pragma("unroll")                                             \
        for (int j = 0; j < 4; ++j) { l[j] = 0.f; g[j] = 0.f; }       \
        _Pragma("unroll")                                             \
        for (int t = 0; t < 8; ++t) {                                 \
            _Pragma("unroll")                                         \
            for (int j = 0; j < 4; ++j) {                             \
                l[j] = fmaf(h0f[t], vv[t + 2*j], l[j]);               \
                g[j] = fmaf(h1f[t], vv[t + 2*j], g[j]);               \
            }                                                         \
        }                                                             \
    }

#define LOAD14(sp, vv)                                                \
    float4 a_ = *reinterpret_cast<const float4*>(sp);                 \
    float4 b_ = *reinterpret_cast<const float4*>((sp) + 4);           \
    float4 c_ = *reinterpret_cast<const float4*>((sp) + 8);           \
    float2 d_ = *reinterpret_cast<const float2*>((sp) + 12);          \
    float vv[14] = {a_.x, a_.y, a_.z, a_.w, b_.x, b_.y, b_.z, b_.w,   \
                    c_.x, c_.y, c_.z, c_.w, d_.x, d_.y};

__global__ __launch_bounds__(BD, 4)
void dwt3_fused(const float* __restrict__ x,
                const float* __restrict__ h0,
                const float* __restrict__ h1,
                float* __restrict__ out) {
    __shared__ __align__(16) float sx[SX_SZ];
    __shared__ __align__(16) float slo1[SLO1_SZ];
    __shared__ __align__(16) float slo2[SLO2_SZ];

    const int tid   = threadIdx.x;
    const int bid   = blockIdx.x;
    const int row   = bid >> 4;
    const int chunk = bid & 15;
    const int base  = chunk * S;
    const size_t rowOff = (size_t)row * N0;

    float h0f[8], h1f[8];
#pragma unroll
    for (int t = 0; t < 8; ++t) { h0f[t] = h0[t]; h1f[t] = h1[t]; }

    // ---- stage x chunk + periodic halo ----
    const float4* x4 = reinterpret_cast<const float4*>(x + rowOff + base);
#pragma unroll
    for (int m = tid; m < S / 4; m += BD) {      // exactly 2 iters
        float4 v = x4[m];
        int p = SX_OFF + 4 * m;
        sx[p] = v.x; sx[p+1] = v.y; sx[p+2] = v.z; sx[p+3] = v.w;
    }
    if (tid < 64) {                              // halo: 25 left, 31 right, 8 pad
        if (tid < 56) {
            int g, p;
            if (tid < 25) { g = base - 25 + tid;       p = tid; }
            else          { g = base + S + (tid - 25); p = SX_OFF + S + (tid - 25); }
            if (g < 0)    g += N0;
            if (g >= N0)  g -= N0;
            sx[p] = x[rowOff + g];
        } else {
            sx[4152 + (tid - 56)] = 0.f;         // pad read by tail quad only
        }
    }
    __syncthreads();

    // ---- level 1: 518 quads; kk = 4u, window sx phys [8u+4 .. 8u+17] ----
    float* hi1 = out + OFF_HI1 + (size_t)row * 32768 + (size_t)chunk * 2048;
    for (int u = tid; u < 518; u += BD) {        // 1 iter (+6 threads 2nd)
        const float* sp = sx + 8 * u + 4;        // byte 32u+16: 16B aligned
        LOAD14(sp, v);
        float l[4], g[4];
        OCT(v, l, g);
        *reinterpret_cast<float4*>(slo1 + 4 * u) =
            make_float4(l[0], l[1], l[2], l[3]);
        int mb = 4 * u - 9;
#pragma unroll
        for (int j = 0; j < 4; ++j) {
            unsigned mm = (unsigned)(mb + j);
            if (mm < 2048u) hi1[mm] = g[j];
        }
    }
    __syncthreads();

    // ---- level 2: 258 quads; jj = 4u, window slo1 phys [8u .. 8u+13] ----
    float* hi2 = out + OFF_HI2 + (size_t)row * 16384 + (size_t)chunk * 1024;
    if (tid < 258) {
        const float* sp = slo1 + 8 * tid;        // byte 32u: aligned
        LOAD14(sp, v);
        float l[4], g[4];
        OCT(v, l, g);
        *reinterpret_cast<float4*>(slo2 + 4 * tid) =
            make_float4(l[0], l[1], l[2], l[3]);
        int mb = 4 * tid - 3;
#pragma unroll
        for (int j = 0; j < 4; ++j) {
            unsigned mm = (unsigned)(mb + j);
            if (mm < 1024u) hi2[mm] = g[j];
        }
    }
    __syncthreads();

    // ---- level 3: 128 quads; i = 4u, window slo2 phys [8u .. 8u+13] ----
    float* lo3 = out + OFF_LO3 + (size_t)row * 8192 + (size_t)chunk * 512;
    float* hi3 = out + OFF_HI3 + (size_t)row * 8192 + (size_t)chunk * 512;
    if (tid < 128) {
        const float* sp = slo2 + 8 * tid;
        LOAD14(sp, v);
        float l[4], g[4];
        OCT(v, l, g);
        *reinterpret_cast<float4*>(lo3 + 4 * tid) =
            make_float4(l[0], l[1], l[2], l[3]);
        *reinterpret_cast<float4*>(hi3 + 4 * tid) =
            make_float4(g[0], g[1], g[2], g[3]);
    }
}

extern "C" void kernel_launch(void* const* d_in, const int* in_sizes, int n_in,
                              void* d_out, int out_size, void* d_ws, size_t ws_size,
                              hipStream_t stream) {
    const float* x  = (const float*)d_in[0];
    const float* h0 = (const float*)d_in[1];
    const float* h1 = (const float*)d_in[2];
    float* out = (float*)d_out;
    (void)in_sizes; (void)n_in; (void)out_size; (void)d_ws; (void)ws_size;

    dim3 grid(1024 * 16);   // 1024 rows x 16 chunks of 4096
    dim3 block(BD);
    dwt3_fused<<<grid, block, 0, stream>>>(x, h0, h1, out);
}